// Round 4
// baseline (221.535 us; speedup 1.0000x reference)
//
#include <hip/hip_runtime.h>
#include <math.h>

// Problem constants
#define B_  8
#define S_  384
#define H_  12
#define HD_ 64
#define E_  768
#define D_  768

typedef float  floatx4 __attribute__((ext_vector_type(4)));
typedef __bf16 bf16x8  __attribute__((ext_vector_type(8)));
typedef unsigned int ux4 __attribute__((ext_vector_type(4)));

__device__ __forceinline__ unsigned short f2bf(float f) {
    union { float f; unsigned u; } x; x.f = f;
    unsigned r = x.u + 0x7fff + ((x.u >> 16) & 1);
    return (unsigned short)(r >> 16);
}
__device__ __forceinline__ float bf2f(unsigned short u) {
    union { unsigned u; float f; } x; x.u = ((unsigned)u) << 16;
    return x.f;
}
__device__ __forceinline__ bf16x8 gld8(const unsigned short* p) {
    return __builtin_bit_cast(bf16x8, *(const ux4*)p);
}
// swizzled chunk address (shorts) for 128B-row tiles staged via global_load_lds
__device__ __forceinline__ int tadr(int row, int cD) {
    return (row * 8 + (cD ^ (row & 7))) * 8;
}
__device__ __forceinline__ bf16x8 lds8(const unsigned short* base, int row, int cD) {
    return __builtin_bit_cast(bf16x8, *(const ux4*)(base + tadr(row, cD)));
}

// ---------------------------------------------------------------------------
// Fused fp32 -> bf16 convert. grid=(576,11).
// ---------------------------------------------------------------------------
__global__ __launch_bounds__(256) void convert_all(
    const float* __restrict__ x,
    const float* __restrict__ Wq, const float* __restrict__ Wk,
    const float* __restrict__ Wv, const float* __restrict__ Wo,
    const float* __restrict__ Wpk, const float* __restrict__ Wpq,
    const float* __restrict__ rel128,
    unsigned short* __restrict__ xb,
    unsigned short* __restrict__ wqb, unsigned short* __restrict__ wkb,
    unsigned short* __restrict__ wvb, unsigned short* __restrict__ wob,
    unsigned short* __restrict__ wpkb, unsigned short* __restrict__ wpqb,
    unsigned short* __restrict__ relb)
{
    const int seg = blockIdx.y;
    const int e = (blockIdx.x * 256 + threadIdx.x) * 4;
    const float* src;
    unsigned short* dst;
    if (seg < 4)       { src = x + (size_t)seg * 589824; dst = xb + (size_t)seg * 589824; }
    else if (seg == 4) { src = Wq;  dst = wqb; }
    else if (seg == 5) { src = Wk;  dst = wkb; }
    else if (seg == 6) { src = Wv;  dst = wvb; }
    else if (seg == 7) { src = Wo;  dst = wob; }
    else if (seg == 8) { src = Wpk; dst = wpkb; }
    else if (seg == 9) { src = Wpq; dst = wpqb; }
    else               { src = rel128; dst = relb; }

    float4 v;
    if (seg == 10 && e >= 767 * 768) v = make_float4(0.f, 0.f, 0.f, 0.f);
    else                             v = *(const float4*)(src + e);
    ushort4 o;
    o.x = f2bf(v.x); o.y = f2bf(v.y); o.z = f2bf(v.z); o.w = f2bf(v.w);
    *(ushort4*)(dst + e) = o;
}

// ---------------------------------------------------------------------------
// Projection GEMMs (Q,K,Vt,pk,pq), 64x128 tile, BK=64, flat grid of 1008:
//   bid <  864 : z = bid/288 (Q,K,Vt), 48 m-tiles x 6 n-tiles
//   bid >= 864 : z = 3 + (bid-864)/72 (pk,pq), 12 m-tiles x 6 n-tiles
// ---------------------------------------------------------------------------
__global__ __launch_bounds__(256) void proj_all(
    const unsigned short* __restrict__ xb, const unsigned short* __restrict__ relb,
    const unsigned short* __restrict__ wq, const unsigned short* __restrict__ wk,
    const unsigned short* __restrict__ wv, const unsigned short* __restrict__ wpk,
    const unsigned short* __restrict__ wpq,
    const float* __restrict__ bq, const float* __restrict__ bk,
    const float* __restrict__ bv, const float* __restrict__ bpk,
    const float* __restrict__ bpq,
    unsigned short* __restrict__ qb, unsigned short* __restrict__ kb,
    unsigned short* __restrict__ vtb, unsigned short* __restrict__ pkb,
    unsigned short* __restrict__ pqb)
{
    const int bid = blockIdx.x;
    int z, mt, nt;
    if (bid < 864) {
        z = bid / 288; const int r = bid - z * 288; mt = r / 6; nt = r - mt * 6;
    } else {
        const int r2 = bid - 864; z = 3 + r2 / 72;
        const int r = r2 % 72; mt = r / 6; nt = r - mt * 6;
    }
    const int m0 = mt * 64, n0 = nt * 128;

    const unsigned short* A = (z < 3) ? xb : relb;
    const unsigned short* W = (z == 0) ? wq : (z == 1) ? wk : (z == 2) ? wv
                            : (z == 3) ? wpk : wpq;
    const float* bias = (z == 0) ? bq : (z == 1) ? bk : (z == 2) ? bv
                      : (z == 3) ? bpk : bpq;
    unsigned short* C = (z == 0) ? qb : (z == 1) ? kb : (z == 2) ? vtb
                      : (z == 3) ? pkb : pqb;

    __shared__ unsigned short As[64 * 64];     //  8 KB
    __shared__ unsigned short Ws[128 * 64];    // 16 KB

    const int tid  = threadIdx.x;
    const int lane = tid & 63;
    const int wv_  = tid >> 6;                 // N-strip of 32
    const int quad = lane >> 4, l16 = lane & 15;

    floatx4 acc[4][2];
#pragma unroll
    for (int i = 0; i < 4; ++i)
#pragma unroll
        for (int j = 0; j < 2; ++j) acc[i][j] = (floatx4){0.f, 0.f, 0.f, 0.f};

    for (int k0 = 0; k0 < 768; k0 += 64) {
        __syncthreads();
#pragma unroll
        for (int r = 0; r < 2; ++r) {
            const int idx = tid + 256 * r;     // 0..511: A 64 rows x 8 chunks
            const int row = idx >> 3, cL = idx & 7, cD = cL ^ (row & 7);
            __builtin_amdgcn_global_load_lds(
                (__attribute__((address_space(1))) void*)(A + (size_t)(m0 + row) * 768 + k0 + cD * 8),
                (__attribute__((address_space(3))) void*)&As[idx * 8], 16, 0, 0);
        }
#pragma unroll
        for (int r = 0; r < 4; ++r) {
            const int idx = tid + 256 * r;     // 0..1023: W 128 rows x 8 chunks
            const int row = idx >> 3, cL = idx & 7, cD = cL ^ (row & 7);
            __builtin_amdgcn_global_load_lds(
                (__attribute__((address_space(1))) void*)(W + (size_t)(n0 + row) * 768 + k0 + cD * 8),
                (__attribute__((address_space(3))) void*)&Ws[idx * 8], 16, 0, 0);
        }
        __syncthreads();

        bf16x8 a[4][2], b[2][2];
#pragma unroll
        for (int mi = 0; mi < 4; ++mi)
#pragma unroll
            for (int kc = 0; kc < 2; ++kc)
                a[mi][kc] = lds8(As, mi * 16 + l16, kc * 4 + quad);
#pragma unroll
        for (int ni = 0; ni < 2; ++ni)
#pragma unroll
            for (int kc = 0; kc < 2; ++kc)
                b[ni][kc] = lds8(Ws, wv_ * 32 + ni * 16 + l16, kc * 4 + quad);
#pragma unroll
        for (int mi = 0; mi < 4; ++mi)
#pragma unroll
            for (int ni = 0; ni < 2; ++ni)
#pragma unroll
                for (int kc = 0; kc < 2; ++kc)
                    acc[mi][ni] = __builtin_amdgcn_mfma_f32_16x16x32_bf16(
                        a[mi][kc], b[ni][kc], acc[mi][ni], 0, 0, 0);
    }

#pragma unroll
    for (int ni = 0; ni < 2; ++ni) {
        const int n = n0 + wv_ * 32 + ni * 16 + l16;
        const float bn = bias[n];
#pragma unroll
        for (int mi = 0; mi < 4; ++mi) {
            const int mbase = m0 + mi * 16 + quad * 4;
            if (z == 2) {
                const int bb = mbase / S_, s = mbase - bb * S_;
                const int h = n >> 6, hd = n & 63;
                ushort4 o;
                o.x = f2bf(acc[mi][ni][0] + bn);
                o.y = f2bf(acc[mi][ni][1] + bn);
                o.z = f2bf(acc[mi][ni][2] + bn);
                o.w = f2bf(acc[mi][ni][3] + bn);
                *(ushort4*)&C[(((size_t)(bb * H_ + h) << 6) + hd) * S_ + s] = o;
            } else if (z < 2) {
#pragma unroll
                for (int reg = 0; reg < 4; ++reg) {
                    const int m = mbase + reg;
                    const int bb = m / S_, s = m - bb * S_;
                    const int h = n >> 6, hd = n & 63;
                    C[(((size_t)(bb * H_ + h) * S_ + s) << 6) + hd] =
                        f2bf(acc[mi][ni][reg] + bn);
                }
            } else {
#pragma unroll
                for (int reg = 0; reg < 4; ++reg)
                    C[(size_t)(mbase + reg) * 768 + n] = f2bf(acc[mi][ni][reg] + bn);
            }
        }
    }
}

// ---------------------------------------------------------------------------
// Output projection: 64x128 tile, BK=64, grid = 288 (48 m-tiles x 6 n-tiles).
// ---------------------------------------------------------------------------
__global__ __launch_bounds__(256) void gemm_out(
    const unsigned short* __restrict__ A, const unsigned short* __restrict__ W,
    const float* __restrict__ bias, float* __restrict__ C)
{
    const int mt = blockIdx.x / 6, nt = blockIdx.x - mt * 6;
    const int m0 = mt * 64, n0 = nt * 128;

    __shared__ unsigned short As[64 * 64];
    __shared__ unsigned short Ws[128 * 64];

    const int tid  = threadIdx.x;
    const int lane = tid & 63;
    const int wv_  = tid >> 6;
    const int quad = lane >> 4, l16 = lane & 15;

    floatx4 acc[4][2];
#pragma unroll
    for (int i = 0; i < 4; ++i)
#pragma unroll
        for (int j = 0; j < 2; ++j) acc[i][j] = (floatx4){0.f, 0.f, 0.f, 0.f};

    for (int k0 = 0; k0 < 768; k0 += 64) {
        __syncthreads();
#pragma unroll
        for (int r = 0; r < 2; ++r) {
            const int idx = tid + 256 * r;
            const int row = idx >> 3, cL = idx & 7, cD = cL ^ (row & 7);
            __builtin_amdgcn_global_load_lds(
                (__attribute__((address_space(1))) void*)(A + (size_t)(m0 + row) * 768 + k0 + cD * 8),
                (__attribute__((address_space(3))) void*)&As[idx * 8], 16, 0, 0);
        }
#pragma unroll
        for (int r = 0; r < 4; ++r) {
            const int idx = tid + 256 * r;
            const int row = idx >> 3, cL = idx & 7, cD = cL ^ (row & 7);
            __builtin_amdgcn_global_load_lds(
                (__attribute__((address_space(1))) void*)(W + (size_t)(n0 + row) * 768 + k0 + cD * 8),
                (__attribute__((address_space(3))) void*)&Ws[idx * 8], 16, 0, 0);
        }
        __syncthreads();

        bf16x8 a[4][2], b[2][2];
#pragma unroll
        for (int mi = 0; mi < 4; ++mi)
#pragma unroll
            for (int kc = 0; kc < 2; ++kc)
                a[mi][kc] = lds8(As, mi * 16 + l16, kc * 4 + quad);
#pragma unroll
        for (int ni = 0; ni < 2; ++ni)
#pragma unroll
            for (int kc = 0; kc < 2; ++kc)
                b[ni][kc] = lds8(Ws, wv_ * 32 + ni * 16 + l16, kc * 4 + quad);
#pragma unroll
        for (int mi = 0; mi < 4; ++mi)
#pragma unroll
            for (int ni = 0; ni < 2; ++ni)
#pragma unroll
                for (int kc = 0; kc < 2; ++kc)
                    acc[mi][ni] = __builtin_amdgcn_mfma_f32_16x16x32_bf16(
                        a[mi][kc], b[ni][kc], acc[mi][ni], 0, 0, 0);
    }

#pragma unroll
    for (int ni = 0; ni < 2; ++ni) {
        const int n = n0 + wv_ * 32 + ni * 16 + l16;
        const float bn = bias[n];
#pragma unroll
        for (int mi = 0; mi < 4; ++mi)
#pragma unroll
            for (int reg = 0; reg < 4; ++reg) {
                const int m = m0 + mi * 16 + quad * 4 + reg;
                C[(size_t)m * 768 + n] = acc[mi][ni][reg] + bn;
            }
    }
}

// ---------------------------------------------------------------------------
// MFMA flash attention, R14: R13 + forced memory-level parallelism.
//   * ALL MFMA operands (qf,kf,pkf,pqf,vtf = 38 x 16B) preloaded into named
//     register arrays up front -> one latency wait instead of ~10 serial ones.
//   * CP scatter made BRANCHLESS: trash row 64 absorbs out-of-range RMWs via
//     cndmask'd address -> whole kernel is one straight-line block, scheduler
//     free to interleave loads/MFMA/LDS.
//   * bias precomputed into biasv[16]+mkbits before MFMA phases (frees the
//     48 metadata VGPRs early).
//   * launch_bounds(256,2): 256-VGPR budget, no spill; trade occupancy for
//     in-wave ILP (R10-R13 showed occupancy is not the binding resource).
// grid = (6 it, 12 h, 48 = b*6+jt); 256 thr = 4 waves. Zero barriers.
// ---------------------------------------------------------------------------
__global__ __launch_bounds__(256, 2) void attn_mfma(
    const unsigned short* __restrict__ qg, const unsigned short* __restrict__ kg,
    const unsigned short* __restrict__ vtg,
    const unsigned short* __restrict__ pkg, const unsigned short* __restrict__ pqg,
    const int* __restrict__ seg, const float* __restrict__ sep,
    const int* __restrict__ mask,
    const float* __restrict__ same_bias, const float* __restrict__ cross_bias,
    const float* __restrict__ sep_scale, const float* __restrict__ sep_decay,
    unsigned short* __restrict__ part_O, float* __restrict__ part_ml)
{
    __shared__ float CP[65 * 68];              // rows 0..63 scores, row 64 trash

    const int tid  = threadIdx.x;
    const int lane = tid & 63, w = tid >> 6;
    const int l16  = lane & 15, quad = lane >> 4;
    const int it = blockIdx.x, h = blockIdx.y;
    const int b  = blockIdx.z / 6, jt = blockIdx.z - 6 * b;
    const int i0 = it * 64, j0 = jt * 64;
    const size_t bh = (size_t)(b * H_ + h);

    const unsigned short* kbase  = kg  + bh * S_ * 64;
    const unsigned short* vtbase = vtg + bh * 64 * S_;
    const int dbase = i0 - j0 + 320;           // pk/pq window base (0..640)

    // ==== preload ALL MFMA operands (independent 16B loads, issued together) ====
    bf16x8 qf[2];
#pragma unroll
    for (int ks = 0; ks < 2; ++ks)
        qf[ks] = gld8(qg + (bh * S_ + i0 + 16 * w + l16) * 64 + ks * 32 + quad * 8);

    bf16x8 kf[4][2];
#pragma unroll
    for (int nj = 0; nj < 4; ++nj)
#pragma unroll
        for (int ks = 0; ks < 2; ++ks)
            kf[nj][ks] = gld8(kbase + (size_t)(j0 + 16 * nj + l16) * 64
                              + ks * 32 + quad * 8);

    bf16x8 pkf[5][2], pqf[5][2];
#pragma unroll
    for (int f = 0; f < 5; ++f)
#pragma unroll
        for (int ks = 0; ks < 2; ++ks) {
            const size_t go = (size_t)(dbase + 16 * (w + f) + l16) * 768
                            + h * 64 + ks * 32 + quad * 8;
            pkf[f][ks] = gld8(pkg + go);
            pqf[f][ks] = gld8(pqg + go);
        }

    bf16x8 vtf[4][2];
#pragma unroll
    for (int nd = 0; nd < 4; ++nd)
#pragma unroll
        for (int ks = 0; ks < 2; ++ks)
            vtf[nd][ks] = gld8(vtbase + (size_t)(16 * nd + l16) * S_
                               + j0 + ks * 32 + quad * 8);

    // ==== metadata + bias precompute (frees metadata regs early) ====
    const int row = 16 * w + l16;              // softmax row this lane owns
    const float aii = fabsf(sep[b * S_ + i0 + row]);
    const int   sii = seg[b * S_ + i0 + row];
    const float* sepj = sep  + b * S_ + j0;
    const int*   segj = seg  + b * S_ + j0;
    const int*   mskj = mask + b * S_ + j0;
    float ajv[16]; int sjv[16], mkv[16];
    *(float4*)&ajv[0]  = *(const float4*)&sepj[quad * 8];
    *(float4*)&ajv[4]  = *(const float4*)&sepj[quad * 8 + 4];
    *(float4*)&ajv[8]  = *(const float4*)&sepj[32 + quad * 8];
    *(float4*)&ajv[12] = *(const float4*)&sepj[32 + quad * 8 + 4];
    *(int4*)&sjv[0]  = *(const int4*)&segj[quad * 8];
    *(int4*)&sjv[4]  = *(const int4*)&segj[quad * 8 + 4];
    *(int4*)&sjv[8]  = *(const int4*)&segj[32 + quad * 8];
    *(int4*)&sjv[12] = *(const int4*)&segj[32 + quad * 8 + 4];
    *(int4*)&mkv[0]  = *(const int4*)&mskj[quad * 8];
    *(int4*)&mkv[4]  = *(const int4*)&mskj[quad * 8 + 4];
    *(int4*)&mkv[8]  = *(const int4*)&mskj[32 + quad * 8];
    *(int4*)&mkv[12] = *(const int4*)&mskj[32 + quad * 8 + 4];

    const float sb  = same_bias[h];
    const float cb  = cross_bias[h];
    const float ssc = sep_scale[h];
    const float sd  = sep_decay[h];
    const float dec = fmaxf(sd, 0.f) + log1pf(__expf(-fabsf(sd))) + 1e-4f;
    const float isc = 0.07216878364870323f;    // 1/sqrt(64*3)

    float biasv[16]; unsigned mkbits = 0;
#pragma unroll
    for (int e = 0; e < 16; ++e) {
        const float gap = fabsf(aii - fabsf(ajv[e]));
        biasv[e] = (sii == sjv[e]) ? sb : cb + __expf(-gap * dec) * ssc;
        mkbits |= (mkv[e] != 0 ? 1u : 0u) << e;
    }

    const int TRASH = 64 * 68;

    // ==== c2c: CP rows strip w = q . k ====
#pragma unroll
    for (int nj = 0; nj < 4; ++nj) {
        floatx4 acc = (floatx4){0.f, 0.f, 0.f, 0.f};
#pragma unroll
        for (int ks = 0; ks < 2; ++ks)
            acc = __builtin_amdgcn_mfma_f32_16x16x32_bf16(qf[ks], kf[nj][ks], acc, 0, 0, 0);
#pragma unroll
        for (int reg = 0; reg < 4; ++reg) {
            const int ii = 16 * w + quad * 4 + reg;
            CP[ii * 68 + 16 * nj + l16] = acc[reg];
        }
    }

    // ==== c2p: frags nd=w..w+4, branchless scatter jj = ii-ddloc+63 ====
#pragma unroll
    for (int f = 0; f < 5; ++f) {
        floatx4 acc = (floatx4){0.f, 0.f, 0.f, 0.f};
#pragma unroll
        for (int ks = 0; ks < 2; ++ks)
            acc = __builtin_amdgcn_mfma_f32_16x16x32_bf16(qf[ks], pkf[f][ks], acc, 0, 0, 0);
        const int ddloc = 16 * (w + f) + l16;
#pragma unroll
        for (int reg = 0; reg < 4; ++reg) {
            const int ii = 16 * w + quad * 4 + reg;
            const int jj = ii - ddloc + 63;
            const bool v = (jj >= 0 && jj < 64);
            const int adr = v ? (ii * 68 + jj) : (TRASH + lane);
            CP[adr] += acc[reg];               // unique writer per real cell
        }
    }

    // ==== p2c: A=PQ (m=ddloc), B=K (n=jj); branchless strip guard ====
#pragma unroll
    for (int f = 0; f < 5; ++f) {
#pragma unroll
        for (int g = 0; g < 2; ++g) {
            const int nj = (g == 0) ? (3 - f) : (4 - f);
            if (nj < 0 || nj > 3) continue;    // compile-time after unroll
            floatx4 acc = (floatx4){0.f, 0.f, 0.f, 0.f};
#pragma unroll
            for (int ks = 0; ks < 2; ++ks)
                acc = __builtin_amdgcn_mfma_f32_16x16x32_bf16(pqf[f][ks], kf[nj][ks], acc, 0, 0, 0);
            const int jj = 16 * nj + l16;
#pragma unroll
            for (int reg = 0; reg < 4; ++reg) {
                const int ddloc = 16 * (w + f) + quad * 4 + reg;
                const int ii = ddloc + jj - 63;
                const bool v = (ii >= 16 * w && ii < 16 * w + 16);
                const int adr = v ? (ii * 68 + jj) : (TRASH + lane);
                CP[adr] += acc[reg];           // unique writer per real cell
            }
        }
    }

    // ==== register softmax: lane owns row `row`, its 16 PV-frag cols ====
    floatx4 cp0 = *(const floatx4*)&CP[row * 68 + quad * 8];
    floatx4 cp1 = *(const floatx4*)&CP[row * 68 + quad * 8 + 4];
    floatx4 cp2 = *(const floatx4*)&CP[row * 68 + 32 + quad * 8];
    floatx4 cp3 = *(const floatx4*)&CP[row * 68 + 32 + quad * 8 + 4];

    float lg[16];
    float tmax = -INFINITY;
#pragma unroll
    for (int e = 0; e < 16; ++e) {
        const float cpv = (e < 4) ? cp0[e] : (e < 8) ? cp1[e - 4]
                        : (e < 12) ? cp2[e - 8] : cp3[e - 12];
        float xv = cpv * isc + biasv[e];
        if (!((mkbits >> e) & 1u)) xv = -9.0e15f;
        lg[e] = xv;
        tmax = fmaxf(tmax, xv);
    }
    tmax = fmaxf(tmax, __shfl_xor(tmax, 16));
    tmax = fmaxf(tmax, __shfl_xor(tmax, 32));

    float rs = 0.f;
    unsigned int pk32[8];
#pragma unroll
    for (int e = 0; e < 8; ++e) {
        const float e0 = __expf(lg[2 * e]     - tmax);
        const float e1 = __expf(lg[2 * e + 1] - tmax);
        rs += e0 + e1;
        pk32[e] = (unsigned)f2bf(e0) | ((unsigned)f2bf(e1) << 16);
    }
    rs += __shfl_xor(rs, 16);
    rs += __shfl_xor(rs, 32);

    float* pml = part_ml + (size_t)(jt * 576 + ((b * H_ + h) * 6 + it)) * 128;
    if (quad == 0) {
        pml[row]      = tmax;
        pml[64 + row] = rs;
    }

    // ==== PV: O = P x Vt; pA straight from registers, vtf preloaded ====
    bf16x8 pA[2];
    pA[0] = __builtin_bit_cast(bf16x8, (ux4){pk32[0], pk32[1], pk32[2], pk32[3]});
    pA[1] = __builtin_bit_cast(bf16x8, (ux4){pk32[4], pk32[5], pk32[6], pk32[7]});
    floatx4 O[4];
#pragma unroll
    for (int nd = 0; nd < 4; ++nd) {
        O[nd] = (floatx4){0.f, 0.f, 0.f, 0.f};
#pragma unroll
        for (int ks = 0; ks < 2; ++ks)
            O[nd] = __builtin_amdgcn_mfma_f32_16x16x32_bf16(pA[ks], vtf[nd][ks], O[nd], 0, 0, 0);
    }

    // ==== epilogue: write unnormalized partial O ====
    unsigned short* pO = part_O + (size_t)(jt * 576 + ((b * H_ + h) * 6 + it)) * 4096;
#pragma unroll
    for (int nd = 0; nd < 4; ++nd) {
        const int d = 16 * nd + l16;
#pragma unroll
        for (int reg = 0; reg < 4; ++reg) {
            const int ii = 16 * w + quad * 4 + reg;
            pO[ii * 64 + d] = f2bf(O[nd][reg]);
        }
    }
}

// ---------------------------------------------------------------------------
// Merge the 6 split-j partials -> vals (bf16, (B,S,E)). grid=576, 256 thr.
// ---------------------------------------------------------------------------
__global__ __launch_bounds__(256) void merge_attn(
    const unsigned short* __restrict__ part_O, const float* __restrict__ part_ml,
    unsigned short* __restrict__ vals)
{
    const int idx = blockIdx.x;                 // ((b*H+h)*6+it)
    const int b  = idx / (H_ * 6);
    const int r  = idx - b * H_ * 6;
    const int h  = r / 6, it = r - h * 6;
    const int tid = threadIdx.x;
    const int ii = tid >> 2, c = (tid & 3) * 16;

    float m[6], l[6];
#pragma unroll
    for (int jc = 0; jc < 6; ++jc) {
        const float* pml = part_ml + (size_t)(jc * 576 + idx) * 128;
        m[jc] = pml[ii];
        l[jc] = pml[64 + ii];
    }
    float M = m[0];
#pragma unroll
    for (int jc = 1; jc < 6; ++jc) M = fmaxf(M, m[jc]);
    float wsum = 0.f, wc[6];
#pragma unroll
    for (int jc = 0; jc < 6; ++jc) {
        wc[jc] = __expf(m[jc] - M);
        wsum += wc[jc] * l[jc];
    }
    const float inv = (wsum > 0.f) ? 1.f / wsum : 0.f;

    float o[16];
#pragma unroll
    for (int e = 0; e < 16; ++e) o[e] = 0.f;
#pragma unroll
    for (int jc = 0; jc < 6; ++jc) {
        const unsigned short* pO = part_O + ((size_t)(jc * 576 + idx)) * 4096
                                 + ii * 64 + c;
        ux4 u0 = *(const ux4*)pO;
        ux4 u1 = *(const ux4*)(pO + 8);
        const unsigned short* us0 = (const unsigned short*)&u0;
        const unsigned short* us1 = (const unsigned short*)&u1;
#pragma unroll
        for (int e = 0; e < 8; ++e) {
            o[e]     += wc[jc] * bf2f(us0[e]);
            o[8 + e] += wc[jc] * bf2f(us1[e]);
        }
    }
    ushort4 w0, w1, w2, w3;
#pragma unroll
    for (int e = 0; e < 4; ++e) {
        ((unsigned short*)&w0)[e] = f2bf(o[e] * inv);
        ((unsigned short*)&w1)[e] = f2bf(o[4 + e] * inv);
        ((unsigned short*)&w2)[e] = f2bf(o[8 + e] * inv);
        ((unsigned short*)&w3)[e] = f2bf(o[12 + e] * inv);
    }
    unsigned short* dst = vals + ((size_t)(b * S_ + it * 64 + ii)) * E_ + h * 64 + c;
    *(ushort4*)(dst)      = w0;
    *(ushort4*)(dst + 4)  = w1;
    *(ushort4*)(dst + 8)  = w2;
    *(ushort4*)(dst + 12) = w3;
}

// ---------------------------------------------------------------------------
// Launcher. Workspace (shorts unless noted): xb 2359296; 7x589824 weights/rel;
// qb,kb,vtb 3x2359296; pkb,pqb 2x589824; valsb 2359296; part_O 6x576x4096;
// part_ml fp32 6x576x128. ~69 MiB.
// ---------------------------------------------------------------------------
extern "C" void kernel_launch(void* const* d_in, const int* in_sizes, int n_in,
                              void* d_out, int out_size, void* d_ws, size_t ws_size,
                              hipStream_t stream)
{
    const float* x         = (const float*)d_in[0];
    const int*   mask      = (const int*)d_in[1];
    const int*   seg       = (const int*)d_in[2];
    const float* sep       = (const float*)d_in[3];
    const float* Wq        = (const float*)d_in[4];
    const float* bq        = (const float*)d_in[5];
    const float* Wk        = (const float*)d_in[6];
    const float* bk        = (const float*)d_in[7];
    const float* Wv        = (const float*)d_in[8];
    const float* bv        = (const float*)d_in[9];
    const float* rel_emb   = (const float*)d_in[10];
    const float* Wpk       = (const float*)d_in[11];
    const float* bpk       = (const float*)d_in[12];
    const float* Wpq       = (const float*)d_in[13];
    const float* bpq       = (const float*)d_in[14];
    const float* same_bias = (const float*)d_in[15];
    const float* cross_bias= (const float*)d_in[16];
    const float* sep_scale = (const float*)d_in[17];
    const float* sep_decay = (const float*)d_in[18];
    const float* Wo        = (const float*)d_in[19];
    const float* bo        = (const float*)d_in[20];

    const size_t QKVN = (size_t)B_ * S_ * E_;   // 2359296
    const size_t WN   = (size_t)768 * 768;      //  589824

    unsigned short* xb    = (unsigned short*)d_ws;
    unsigned short* wqb   = xb   + QKVN;
    unsigned short* wkb   = wqb  + WN;
    unsigned short* wvb   = wkb  + WN;
    unsigned short* wob   = wvb  + WN;
    unsigned short* wpkb  = wob  + WN;
    unsigned short* wpqb  = wpkb + WN;
    unsigned short* relb  = wpqb + WN;
    unsigned short* qb    = relb + WN;
    unsigned short* kb    = qb   + QKVN;
    unsigned short* vtb   = kb   + QKVN;
    unsigned short* pkb   = vtb  + QKVN;
    unsigned short* pqb   = pkb  + WN;
    unsigned short* valsb = pqb  + WN;
    unsigned short* partO = valsb + QKVN;                       // 6*576*4096 shorts
    float*          partml= (float*)(partO + (size_t)6 * 576 * 4096);

    // 1) convert all operands to bf16
    convert_all<<<dim3(576, 11), 256, 0, stream>>>(
        x, Wq, Wk, Wv, Wo, Wpk, Wpq, rel_emb + (size_t)128 * D_,
        xb, wqb, wkb, wvb, wob, wpkb, wpqb, relb);

    // 2) fused Q/K/Vt/pk/pq projections (64x128 tiles, 1008 blocks)
    proj_all<<<dim3(1008), 256, 0, stream>>>(
        xb, relb, wqb, wkb, wvb, wpkb, wpqb,
        bq, bk, bv, bpk, bpq, qb, kb, vtb, pkb, pqb);

    // 3) MFMA flash attention (R14: preloaded operands, branchless scatter)
    attn_mfma<<<dim3(6, 12, 48), 256, 0, stream>>>(
        qb, kb, vtb, pkb, pqb, seg, sep, mask,
        same_bias, cross_bias, sep_scale, sep_decay, partO, partml);

    // 4) merge partials -> valsb
    merge_attn<<<dim3(576), 256, 0, stream>>>(partO, partml, valsb);

    // 5) output projection (64x128 tiles, 288 blocks)
    gemm_out<<<dim3(288), 256, 0, stream>>>(valsb, wob, bo, (float*)d_out);
}

// Round 5
// 200.388 us; speedup vs baseline: 1.1055x; 1.1055x over previous
//
#include <hip/hip_runtime.h>
#include <math.h>

// Problem constants
#define B_  8
#define S_  384
#define H_  12
#define HD_ 64
#define E_  768
#define D_  768

typedef float  floatx4 __attribute__((ext_vector_type(4)));
typedef __bf16 bf16x8  __attribute__((ext_vector_type(8)));
typedef unsigned int ux4 __attribute__((ext_vector_type(4)));

__device__ __forceinline__ unsigned short f2bf(float f) {
    union { float f; unsigned u; } x; x.f = f;
    unsigned r = x.u + 0x7fff + ((x.u >> 16) & 1);
    return (unsigned short)(r >> 16);
}
__device__ __forceinline__ float bf2f(unsigned short u) {
    union { unsigned u; float f; } x; x.u = ((unsigned)u) << 16;
    return x.f;
}
__device__ __forceinline__ bf16x8 gld8(const unsigned short* p) {
    return __builtin_bit_cast(bf16x8, *(const ux4*)p);
}
// swizzled chunk address (shorts) for 128B-row tiles staged via global_load_lds
__device__ __forceinline__ int tadr(int row, int cD) {
    return (row * 8 + (cD ^ (row & 7))) * 8;
}
__device__ __forceinline__ bf16x8 lds8(const unsigned short* base, int row, int cD) {
    return __builtin_bit_cast(bf16x8, *(const ux4*)(base + tadr(row, cD)));
}

// ---------------------------------------------------------------------------
// Fused fp32 -> bf16 convert. grid=(576,11).
// ---------------------------------------------------------------------------
__global__ __launch_bounds__(256) void convert_all(
    const float* __restrict__ x,
    const float* __restrict__ Wq, const float* __restrict__ Wk,
    const float* __restrict__ Wv, const float* __restrict__ Wo,
    const float* __restrict__ Wpk, const float* __restrict__ Wpq,
    const float* __restrict__ rel128,
    unsigned short* __restrict__ xb,
    unsigned short* __restrict__ wqb, unsigned short* __restrict__ wkb,
    unsigned short* __restrict__ wvb, unsigned short* __restrict__ wob,
    unsigned short* __restrict__ wpkb, unsigned short* __restrict__ wpqb,
    unsigned short* __restrict__ relb)
{
    const int seg = blockIdx.y;
    const int e = (blockIdx.x * 256 + threadIdx.x) * 4;
    const float* src;
    unsigned short* dst;
    if (seg < 4)       { src = x + (size_t)seg * 589824; dst = xb + (size_t)seg * 589824; }
    else if (seg == 4) { src = Wq;  dst = wqb; }
    else if (seg == 5) { src = Wk;  dst = wkb; }
    else if (seg == 6) { src = Wv;  dst = wvb; }
    else if (seg == 7) { src = Wo;  dst = wob; }
    else if (seg == 8) { src = Wpk; dst = wpkb; }
    else if (seg == 9) { src = Wpq; dst = wpqb; }
    else               { src = rel128; dst = relb; }

    float4 v;
    if (seg == 10 && e >= 767 * 768) v = make_float4(0.f, 0.f, 0.f, 0.f);
    else                             v = *(const float4*)(src + e);
    ushort4 o;
    o.x = f2bf(v.x); o.y = f2bf(v.y); o.z = f2bf(v.z); o.w = f2bf(v.w);
    *(ushort4*)(dst + e) = o;
}

// ---------------------------------------------------------------------------
// Projection GEMMs (Q,K,Vt,pk,pq), 64x128 tile, BK=64, flat grid of 1008:
//   bid <  864 : z = bid/288 (Q,K,Vt), 48 m-tiles x 6 n-tiles
//   bid >= 864 : z = 3 + (bid-864)/72 (pk,pq), 12 m-tiles x 6 n-tiles
// ---------------------------------------------------------------------------
__global__ __launch_bounds__(256) void proj_all(
    const unsigned short* __restrict__ xb, const unsigned short* __restrict__ relb,
    const unsigned short* __restrict__ wq, const unsigned short* __restrict__ wk,
    const unsigned short* __restrict__ wv, const unsigned short* __restrict__ wpk,
    const unsigned short* __restrict__ wpq,
    const float* __restrict__ bq, const float* __restrict__ bk,
    const float* __restrict__ bv, const float* __restrict__ bpk,
    const float* __restrict__ bpq,
    unsigned short* __restrict__ qb, unsigned short* __restrict__ kb,
    unsigned short* __restrict__ vtb, unsigned short* __restrict__ pkb,
    unsigned short* __restrict__ pqb)
{
    const int bid = blockIdx.x;
    int z, mt, nt;
    if (bid < 864) {
        z = bid / 288; const int r = bid - z * 288; mt = r / 6; nt = r - mt * 6;
    } else {
        const int r2 = bid - 864; z = 3 + r2 / 72;
        const int r = r2 % 72; mt = r / 6; nt = r - mt * 6;
    }
    const int m0 = mt * 64, n0 = nt * 128;

    const unsigned short* A = (z < 3) ? xb : relb;
    const unsigned short* W = (z == 0) ? wq : (z == 1) ? wk : (z == 2) ? wv
                            : (z == 3) ? wpk : wpq;
    const float* bias = (z == 0) ? bq : (z == 1) ? bk : (z == 2) ? bv
                      : (z == 3) ? bpk : bpq;
    unsigned short* C = (z == 0) ? qb : (z == 1) ? kb : (z == 2) ? vtb
                      : (z == 3) ? pkb : pqb;

    __shared__ unsigned short As[64 * 64];     //  8 KB
    __shared__ unsigned short Ws[128 * 64];    // 16 KB

    const int tid  = threadIdx.x;
    const int lane = tid & 63;
    const int wv_  = tid >> 6;                 // N-strip of 32
    const int quad = lane >> 4, l16 = lane & 15;

    floatx4 acc[4][2];
#pragma unroll
    for (int i = 0; i < 4; ++i)
#pragma unroll
        for (int j = 0; j < 2; ++j) acc[i][j] = (floatx4){0.f, 0.f, 0.f, 0.f};

    for (int k0 = 0; k0 < 768; k0 += 64) {
        __syncthreads();
#pragma unroll
        for (int r = 0; r < 2; ++r) {
            const int idx = tid + 256 * r;     // 0..511: A 64 rows x 8 chunks
            const int row = idx >> 3, cL = idx & 7, cD = cL ^ (row & 7);
            __builtin_amdgcn_global_load_lds(
                (__attribute__((address_space(1))) void*)(A + (size_t)(m0 + row) * 768 + k0 + cD * 8),
                (__attribute__((address_space(3))) void*)&As[idx * 8], 16, 0, 0);
        }
#pragma unroll
        for (int r = 0; r < 4; ++r) {
            const int idx = tid + 256 * r;     // 0..1023: W 128 rows x 8 chunks
            const int row = idx >> 3, cL = idx & 7, cD = cL ^ (row & 7);
            __builtin_amdgcn_global_load_lds(
                (__attribute__((address_space(1))) void*)(W + (size_t)(n0 + row) * 768 + k0 + cD * 8),
                (__attribute__((address_space(3))) void*)&Ws[idx * 8], 16, 0, 0);
        }
        __syncthreads();

        bf16x8 a[4][2], b[2][2];
#pragma unroll
        for (int mi = 0; mi < 4; ++mi)
#pragma unroll
            for (int kc = 0; kc < 2; ++kc)
                a[mi][kc] = lds8(As, mi * 16 + l16, kc * 4 + quad);
#pragma unroll
        for (int ni = 0; ni < 2; ++ni)
#pragma unroll
            for (int kc = 0; kc < 2; ++kc)
                b[ni][kc] = lds8(Ws, wv_ * 32 + ni * 16 + l16, kc * 4 + quad);
#pragma unroll
        for (int mi = 0; mi < 4; ++mi)
#pragma unroll
            for (int ni = 0; ni < 2; ++ni)
#pragma unroll
                for (int kc = 0; kc < 2; ++kc)
                    acc[mi][ni] = __builtin_amdgcn_mfma_f32_16x16x32_bf16(
                        a[mi][kc], b[ni][kc], acc[mi][ni], 0, 0, 0);
    }

#pragma unroll
    for (int ni = 0; ni < 2; ++ni) {
        const int n = n0 + wv_ * 32 + ni * 16 + l16;
        const float bn = bias[n];
#pragma unroll
        for (int mi = 0; mi < 4; ++mi) {
            const int mbase = m0 + mi * 16 + quad * 4;
            if (z == 2) {
                const int bb = mbase / S_, s = mbase - bb * S_;
                const int h = n >> 6, hd = n & 63;
                ushort4 o;
                o.x = f2bf(acc[mi][ni][0] + bn);
                o.y = f2bf(acc[mi][ni][1] + bn);
                o.z = f2bf(acc[mi][ni][2] + bn);
                o.w = f2bf(acc[mi][ni][3] + bn);
                *(ushort4*)&C[(((size_t)(bb * H_ + h) << 6) + hd) * S_ + s] = o;
            } else if (z < 2) {
#pragma unroll
                for (int reg = 0; reg < 4; ++reg) {
                    const int m = mbase + reg;
                    const int bb = m / S_, s = m - bb * S_;
                    const int h = n >> 6, hd = n & 63;
                    C[(((size_t)(bb * H_ + h) * S_ + s) << 6) + hd] =
                        f2bf(acc[mi][ni][reg] + bn);
                }
            } else {
#pragma unroll
                for (int reg = 0; reg < 4; ++reg)
                    C[(size_t)(mbase + reg) * 768 + n] = f2bf(acc[mi][ni][reg] + bn);
            }
        }
    }
}

// ---------------------------------------------------------------------------
// Output projection: 64x128 tile, BK=64, grid = 288 (48 m-tiles x 6 n-tiles).
// ---------------------------------------------------------------------------
__global__ __launch_bounds__(256) void gemm_out(
    const unsigned short* __restrict__ A, const unsigned short* __restrict__ W,
    const float* __restrict__ bias, float* __restrict__ C)
{
    const int mt = blockIdx.x / 6, nt = blockIdx.x - mt * 6;
    const int m0 = mt * 64, n0 = nt * 128;

    __shared__ unsigned short As[64 * 64];
    __shared__ unsigned short Ws[128 * 64];

    const int tid  = threadIdx.x;
    const int lane = tid & 63;
    const int wv_  = tid >> 6;
    const int quad = lane >> 4, l16 = lane & 15;

    floatx4 acc[4][2];
#pragma unroll
    for (int i = 0; i < 4; ++i)
#pragma unroll
        for (int j = 0; j < 2; ++j) acc[i][j] = (floatx4){0.f, 0.f, 0.f, 0.f};

    for (int k0 = 0; k0 < 768; k0 += 64) {
        __syncthreads();
#pragma unroll
        for (int r = 0; r < 2; ++r) {
            const int idx = tid + 256 * r;
            const int row = idx >> 3, cL = idx & 7, cD = cL ^ (row & 7);
            __builtin_amdgcn_global_load_lds(
                (__attribute__((address_space(1))) void*)(A + (size_t)(m0 + row) * 768 + k0 + cD * 8),
                (__attribute__((address_space(3))) void*)&As[idx * 8], 16, 0, 0);
        }
#pragma unroll
        for (int r = 0; r < 4; ++r) {
            const int idx = tid + 256 * r;
            const int row = idx >> 3, cL = idx & 7, cD = cL ^ (row & 7);
            __builtin_amdgcn_global_load_lds(
                (__attribute__((address_space(1))) void*)(W + (size_t)(n0 + row) * 768 + k0 + cD * 8),
                (__attribute__((address_space(3))) void*)&Ws[idx * 8], 16, 0, 0);
        }
        __syncthreads();

        bf16x8 a[4][2], b[2][2];
#pragma unroll
        for (int mi = 0; mi < 4; ++mi)
#pragma unroll
            for (int kc = 0; kc < 2; ++kc)
                a[mi][kc] = lds8(As, mi * 16 + l16, kc * 4 + quad);
#pragma unroll
        for (int ni = 0; ni < 2; ++ni)
#pragma unroll
            for (int kc = 0; kc < 2; ++kc)
                b[ni][kc] = lds8(Ws, wv_ * 32 + ni * 16 + l16, kc * 4 + quad);
#pragma unroll
        for (int mi = 0; mi < 4; ++mi)
#pragma unroll
            for (int ni = 0; ni < 2; ++ni)
#pragma unroll
                for (int kc = 0; kc < 2; ++kc)
                    acc[mi][ni] = __builtin_amdgcn_mfma_f32_16x16x32_bf16(
                        a[mi][kc], b[ni][kc], acc[mi][ni], 0, 0, 0);
    }

#pragma unroll
    for (int ni = 0; ni < 2; ++ni) {
        const int n = n0 + wv_ * 32 + ni * 16 + l16;
        const float bn = bias[n];
#pragma unroll
        for (int mi = 0; mi < 4; ++mi)
#pragma unroll
            for (int reg = 0; reg < 4; ++reg) {
                const int m = m0 + mi * 16 + quad * 4 + reg;
                C[(size_t)m * 768 + n] = acc[mi][ni][reg] + bn;
            }
    }
}

// ---------------------------------------------------------------------------
// MFMA flash attention, R15: R13 (register softmax, guarded scatter, split-j 6)
// + PK/PQ staged via global_load_lds (DMA path). Rationale (R14 post-mortem):
// the kernel is bound by per-CU vector-memory REQUEST throughput, not latency
// or occupancy. PK/PQ gathers were the worst offenders (20 instr/wave x 16
// cache lines, 2.5x row overlap across waves = ~1280 line-req/block). Staging
// them costs ~256 contiguous line-req/block. q/k/vt/metadata stay direct and
// fly during the staging; c2c (needs only q,k) runs BEFORE the one barrier.
// LDS = PKs 16K + PQs 16K + CP 17K = 49 KB -> 3 blocks/CU.
// grid = (6 it, 12 h, 48 = b*6+jt); 256 thr = 4 waves. ONE barrier.
// ---------------------------------------------------------------------------
__global__ __launch_bounds__(256, 3) void attn_mfma(
    const unsigned short* __restrict__ qg, const unsigned short* __restrict__ kg,
    const unsigned short* __restrict__ vtg,
    const unsigned short* __restrict__ pkg, const unsigned short* __restrict__ pqg,
    const int* __restrict__ seg, const float* __restrict__ sep,
    const int* __restrict__ mask,
    const float* __restrict__ same_bias, const float* __restrict__ cross_bias,
    const float* __restrict__ sep_scale, const float* __restrict__ sep_decay,
    unsigned short* __restrict__ part_O, float* __restrict__ part_ml)
{
    __shared__ unsigned short PKs[128 * 64];   // 16 KB, swizzled chunks
    __shared__ unsigned short PQs[128 * 64];   // 16 KB
    __shared__ float CP[64 * 68];              // 17 KB score tile

    const int tid  = threadIdx.x;
    const int lane = tid & 63, w = tid >> 6;
    const int l16  = lane & 15, quad = lane >> 4;
    const int it = blockIdx.x, h = blockIdx.y;
    const int b  = blockIdx.z / 6, jt = blockIdx.z - 6 * b;
    const int i0 = it * 64, j0 = jt * 64;
    const size_t bh = (size_t)(b * H_ + h);

    const unsigned short* kbase  = kg  + bh * S_ * 64;
    const unsigned short* vtbase = vtg + bh * 64 * S_;
    const int dbase = i0 - j0 + 320;           // pk/pq window base (0..640)

    // ---- stage PK + PQ (128 rows x 128B each) via global_load_lds DMA ----
#pragma unroll
    for (int r = 0; r < 4; ++r) {
        const int idx = tid + 256 * r;         // 0..1023: 128 rows x 8 chunks
        const int srow = idx >> 3, cL = idx & 7, cD = cL ^ (srow & 7);
        const size_t go = (size_t)(dbase + srow) * 768 + h * 64 + cD * 8;
        __builtin_amdgcn_global_load_lds(
            (__attribute__((address_space(1))) void*)(pkg + go),
            (__attribute__((address_space(3))) void*)&PKs[idx * 8], 16, 0, 0);
        __builtin_amdgcn_global_load_lds(
            (__attribute__((address_space(1))) void*)(pqg + go),
            (__attribute__((address_space(3))) void*)&PQs[idx * 8], 16, 0, 0);
    }

    // ---- direct loads (fly during staging): Q, K, Vt fragments ----
    bf16x8 qf[2];
#pragma unroll
    for (int ks = 0; ks < 2; ++ks)
        qf[ks] = gld8(qg + (bh * S_ + i0 + 16 * w + l16) * 64 + ks * 32 + quad * 8);

    bf16x8 kf[4][2];
#pragma unroll
    for (int nj = 0; nj < 4; ++nj)
#pragma unroll
        for (int ks = 0; ks < 2; ++ks)
            kf[nj][ks] = gld8(kbase + (size_t)(j0 + 16 * nj + l16) * 64
                              + ks * 32 + quad * 8);

    bf16x8 vtf[4][2];
#pragma unroll
    for (int nd = 0; nd < 4; ++nd)
#pragma unroll
        for (int ks = 0; ks < 2; ++ks)
            vtf[nd][ks] = gld8(vtbase + (size_t)(16 * nd + l16) * S_
                               + j0 + ks * 32 + quad * 8);

    // ---- metadata (also in flight) ----
    const int row = 16 * w + l16;              // softmax row this lane owns
    const float aii = fabsf(sep[b * S_ + i0 + row]);
    const int   sii = seg[b * S_ + i0 + row];
    const float* sepj = sep  + b * S_ + j0;
    const int*   segj = seg  + b * S_ + j0;
    const int*   mskj = mask + b * S_ + j0;
    float ajv[16]; int sjv[16], mkv[16];
    *(float4*)&ajv[0]  = *(const float4*)&sepj[quad * 8];
    *(float4*)&ajv[4]  = *(const float4*)&sepj[quad * 8 + 4];
    *(float4*)&ajv[8]  = *(const float4*)&sepj[32 + quad * 8];
    *(float4*)&ajv[12] = *(const float4*)&sepj[32 + quad * 8 + 4];
    *(int4*)&sjv[0]  = *(const int4*)&segj[quad * 8];
    *(int4*)&sjv[4]  = *(const int4*)&segj[quad * 8 + 4];
    *(int4*)&sjv[8]  = *(const int4*)&segj[32 + quad * 8];
    *(int4*)&sjv[12] = *(const int4*)&segj[32 + quad * 8 + 4];
    *(int4*)&mkv[0]  = *(const int4*)&mskj[quad * 8];
    *(int4*)&mkv[4]  = *(const int4*)&mskj[quad * 8 + 4];
    *(int4*)&mkv[8]  = *(const int4*)&mskj[32 + quad * 8];
    *(int4*)&mkv[12] = *(const int4*)&mskj[32 + quad * 8 + 4];

    const float sb  = same_bias[h];
    const float cb  = cross_bias[h];
    const float ssc = sep_scale[h];
    const float sd  = sep_decay[h];
    const float dec = fmaxf(sd, 0.f) + log1pf(__expf(-fabsf(sd))) + 1e-4f;
    const float isc = 0.07216878364870323f;    // 1/sqrt(64*3)

    // bias precompute (VALU work during staging flight)
    float biasv[16]; unsigned mkbits = 0;
#pragma unroll
    for (int e = 0; e < 16; ++e) {
        const float gap = fabsf(aii - fabsf(ajv[e]));
        biasv[e] = (sii == sjv[e]) ? sb : cb + __expf(-gap * dec) * ssc;
        mkbits |= (mkv[e] != 0 ? 1u : 0u) << e;
    }

    // ---- c2c (needs only qf,kf): runs BEFORE the barrier, covers staging ----
#pragma unroll
    for (int nj = 0; nj < 4; ++nj) {
        floatx4 acc = (floatx4){0.f, 0.f, 0.f, 0.f};
#pragma unroll
        for (int ks = 0; ks < 2; ++ks)
            acc = __builtin_amdgcn_mfma_f32_16x16x32_bf16(qf[ks], kf[nj][ks], acc, 0, 0, 0);
#pragma unroll
        for (int reg = 0; reg < 4; ++reg) {
            const int ii = 16 * w + quad * 4 + reg;
            CP[ii * 68 + 16 * nj + l16] = acc[reg];
        }
    }

    __syncthreads();   // the ONE barrier: PK/PQ staging complete

    // ---- c2p (rows strip w): frags nd = w..w+4, scatter jj = ii-ddloc+63 ----
#pragma unroll
    for (int f = 0; f < 5; ++f) {
        const int nd = w + f;
        floatx4 acc = (floatx4){0.f, 0.f, 0.f, 0.f};
#pragma unroll
        for (int ks = 0; ks < 2; ++ks) {
            bf16x8 bf = lds8(PKs, 16 * nd + l16, ks * 4 + quad);
            acc = __builtin_amdgcn_mfma_f32_16x16x32_bf16(qf[ks], bf, acc, 0, 0, 0);
        }
        const int ddloc = 16 * nd + l16;
#pragma unroll
        for (int reg = 0; reg < 4; ++reg) {
            const int ii = 16 * w + quad * 4 + reg;
            const int jj = ii - ddloc + 63;
            if (jj >= 0 && jj < 64)
                CP[ii * 68 + jj] += acc[reg];      // unique writer per cell
        }
    }

    // ---- p2c (rows strip w): A=PQ (m=ddloc), B=K (n=jj) ----
#pragma unroll
    for (int f = 0; f < 5; ++f) {
        const int nd = w + f;
        bf16x8 pqf[2];
#pragma unroll
        for (int ks = 0; ks < 2; ++ks)
            pqf[ks] = lds8(PQs, 16 * nd + l16, ks * 4 + quad);
#pragma unroll
        for (int g = 0; g < 2; ++g) {
            const int nj = (g == 0) ? (3 - f) : (4 - f);
            if (nj < 0 || nj > 3) continue;
            floatx4 acc = (floatx4){0.f, 0.f, 0.f, 0.f};
#pragma unroll
            for (int ks = 0; ks < 2; ++ks)
                acc = __builtin_amdgcn_mfma_f32_16x16x32_bf16(pqf[ks], kf[nj][ks], acc, 0, 0, 0);
            const int jj = 16 * nj + l16;
#pragma unroll
            for (int reg = 0; reg < 4; ++reg) {
                const int ddloc = 16 * nd + quad * 4 + reg;
                const int ii = ddloc + jj - 63;
                if (ii >= 16 * w && ii < 16 * w + 16)
                    CP[ii * 68 + jj] += acc[reg];  // unique writer per cell
            }
        }
    }

    // ---- register softmax: lane owns row `row`, its 16 PV-frag cols ----
    floatx4 cp0 = *(const floatx4*)&CP[row * 68 + quad * 8];
    floatx4 cp1 = *(const floatx4*)&CP[row * 68 + quad * 8 + 4];
    floatx4 cp2 = *(const floatx4*)&CP[row * 68 + 32 + quad * 8];
    floatx4 cp3 = *(const floatx4*)&CP[row * 68 + 32 + quad * 8 + 4];

    float lg[16];
    float tmax = -INFINITY;
#pragma unroll
    for (int e = 0; e < 16; ++e) {
        const float cpv = (e < 4) ? cp0[e] : (e < 8) ? cp1[e - 4]
                        : (e < 12) ? cp2[e - 8] : cp3[e - 12];
        float xv = cpv * isc + biasv[e];
        if (!((mkbits >> e) & 1u)) xv = -9.0e15f;
        lg[e] = xv;
        tmax = fmaxf(tmax, xv);
    }
    tmax = fmaxf(tmax, __shfl_xor(tmax, 16));
    tmax = fmaxf(tmax, __shfl_xor(tmax, 32));

    float rs = 0.f;
    unsigned int pk32[8];
#pragma unroll
    for (int e = 0; e < 8; ++e) {
        const float e0 = __expf(lg[2 * e]     - tmax);
        const float e1 = __expf(lg[2 * e + 1] - tmax);
        rs += e0 + e1;
        pk32[e] = (unsigned)f2bf(e0) | ((unsigned)f2bf(e1) << 16);
    }
    rs += __shfl_xor(rs, 16);
    rs += __shfl_xor(rs, 32);

    float* pml = part_ml + (size_t)(jt * 576 + ((b * H_ + h) * 6 + it)) * 128;
    if (quad == 0) {
        pml[row]      = tmax;
        pml[64 + row] = rs;
    }

    // ---- PV: O = P x Vt; pA straight from registers, vtf preloaded ----
    bf16x8 pA[2];
    pA[0] = __builtin_bit_cast(bf16x8, (ux4){pk32[0], pk32[1], pk32[2], pk32[3]});
    pA[1] = __builtin_bit_cast(bf16x8, (ux4){pk32[4], pk32[5], pk32[6], pk32[7]});
    floatx4 O[4];
#pragma unroll
    for (int nd = 0; nd < 4; ++nd) {
        O[nd] = (floatx4){0.f, 0.f, 0.f, 0.f};
#pragma unroll
        for (int ks = 0; ks < 2; ++ks)
            O[nd] = __builtin_amdgcn_mfma_f32_16x16x32_bf16(pA[ks], vtf[nd][ks], O[nd], 0, 0, 0);
    }

    // ---- epilogue: write unnormalized partial O ----
    unsigned short* pO = part_O + (size_t)(jt * 576 + ((b * H_ + h) * 6 + it)) * 4096;
#pragma unroll
    for (int nd = 0; nd < 4; ++nd) {
        const int d = 16 * nd + l16;
#pragma unroll
        for (int reg = 0; reg < 4; ++reg) {
            const int ii = 16 * w + quad * 4 + reg;
            pO[ii * 64 + d] = f2bf(O[nd][reg]);
        }
    }
}

// ---------------------------------------------------------------------------
// Merge the 6 split-j partials -> vals (bf16, (B,S,E)). grid=576, 256 thr.
// ---------------------------------------------------------------------------
__global__ __launch_bounds__(256) void merge_attn(
    const unsigned short* __restrict__ part_O, const float* __restrict__ part_ml,
    unsigned short* __restrict__ vals)
{
    const int idx = blockIdx.x;                 // ((b*H+h)*6+it)
    const int b  = idx / (H_ * 6);
    const int r  = idx - b * H_ * 6;
    const int h  = r / 6, it = r - h * 6;
    const int tid = threadIdx.x;
    const int ii = tid >> 2, c = (tid & 3) * 16;

    float m[6], l[6];
#pragma unroll
    for (int jc = 0; jc < 6; ++jc) {
        const float* pml = part_ml + (size_t)(jc * 576 + idx) * 128;
        m[jc] = pml[ii];
        l[jc] = pml[64 + ii];
    }
    float M = m[0];
#pragma unroll
    for (int jc = 1; jc < 6; ++jc) M = fmaxf(M, m[jc]);
    float wsum = 0.f, wc[6];
#pragma unroll
    for (int jc = 0; jc < 6; ++jc) {
        wc[jc] = __expf(m[jc] - M);
        wsum += wc[jc] * l[jc];
    }
    const float inv = (wsum > 0.f) ? 1.f / wsum : 0.f;

    float o[16];
#pragma unroll
    for (int e = 0; e < 16; ++e) o[e] = 0.f;
#pragma unroll
    for (int jc = 0; jc < 6; ++jc) {
        const unsigned short* pO = part_O + ((size_t)(jc * 576 + idx)) * 4096
                                 + ii * 64 + c;
        ux4 u0 = *(const ux4*)pO;
        ux4 u1 = *(const ux4*)(pO + 8);
        const unsigned short* us0 = (const unsigned short*)&u0;
        const unsigned short* us1 = (const unsigned short*)&u1;
#pragma unroll
        for (int e = 0; e < 8; ++e) {
            o[e]     += wc[jc] * bf2f(us0[e]);
            o[8 + e] += wc[jc] * bf2f(us1[e]);
        }
    }
    ushort4 w0, w1, w2, w3;
#pragma unroll
    for (int e = 0; e < 4; ++e) {
        ((unsigned short*)&w0)[e] = f2bf(o[e] * inv);
        ((unsigned short*)&w1)[e] = f2bf(o[4 + e] * inv);
        ((unsigned short*)&w2)[e] = f2bf(o[8 + e] * inv);
        ((unsigned short*)&w3)[e] = f2bf(o[12 + e] * inv);
    }
    unsigned short* dst = vals + ((size_t)(b * S_ + it * 64 + ii)) * E_ + h * 64 + c;
    *(ushort4*)(dst)      = w0;
    *(ushort4*)(dst + 4)  = w1;
    *(ushort4*)(dst + 8)  = w2;
    *(ushort4*)(dst + 12) = w3;
}

// ---------------------------------------------------------------------------
// Launcher. Workspace (shorts unless noted): xb 2359296; 7x589824 weights/rel;
// qb,kb,vtb 3x2359296; pkb,pqb 2x589824; valsb 2359296; part_O 6x576x4096;
// part_ml fp32 6x576x128. ~69 MiB.
// ---------------------------------------------------------------------------
extern "C" void kernel_launch(void* const* d_in, const int* in_sizes, int n_in,
                              void* d_out, int out_size, void* d_ws, size_t ws_size,
                              hipStream_t stream)
{
    const float* x         = (const float*)d_in[0];
    const int*   mask      = (const int*)d_in[1];
    const int*   seg       = (const int*)d_in[2];
    const float* sep       = (const float*)d_in[3];
    const float* Wq        = (const float*)d_in[4];
    const float* bq        = (const float*)d_in[5];
    const float* Wk        = (const float*)d_in[6];
    const float* bk        = (const float*)d_in[7];
    const float* Wv        = (const float*)d_in[8];
    const float* bv        = (const float*)d_in[9];
    const float* rel_emb   = (const float*)d_in[10];
    const float* Wpk       = (const float*)d_in[11];
    const float* bpk       = (const float*)d_in[12];
    const float* Wpq       = (const float*)d_in[13];
    const float* bpq       = (const float*)d_in[14];
    const float* same_bias = (const float*)d_in[15];
    const float* cross_bias= (const float*)d_in[16];
    const float* sep_scale = (const float*)d_in[17];
    const float* sep_decay = (const float*)d_in[18];
    const float* Wo        = (const float*)d_in[19];
    const float* bo        = (const float*)d_in[20];

    const size_t QKVN = (size_t)B_ * S_ * E_;   // 2359296
    const size_t WN   = (size_t)768 * 768;      //  589824

    unsigned short* xb    = (unsigned short*)d_ws;
    unsigned short* wqb   = xb   + QKVN;
    unsigned short* wkb   = wqb  + WN;
    unsigned short* wvb   = wkb  + WN;
    unsigned short* wob   = wvb  + WN;
    unsigned short* wpkb  = wob  + WN;
    unsigned short* wpqb  = wpkb + WN;
    unsigned short* relb  = wpqb + WN;
    unsigned short* qb    = relb + WN;
    unsigned short* kb    = qb   + QKVN;
    unsigned short* vtb   = kb   + QKVN;
    unsigned short* pkb   = vtb  + QKVN;
    unsigned short* pqb   = pkb  + WN;
    unsigned short* valsb = pqb  + WN;
    unsigned short* partO = valsb + QKVN;                       // 6*576*4096 shorts
    float*          partml= (float*)(partO + (size_t)6 * 576 * 4096);

    // 1) convert all operands to bf16
    convert_all<<<dim3(576, 11), 256, 0, stream>>>(
        x, Wq, Wk, Wv, Wo, Wpk, Wpq, rel_emb + (size_t)128 * D_,
        xb, wqb, wkb, wvb, wob, wpkb, wpqb, relb);

    // 2) fused Q/K/Vt/pk/pq projections (64x128 tiles, 1008 blocks)
    proj_all<<<dim3(1008), 256, 0, stream>>>(
        xb, relb, wqb, wkb, wvb, wpkb, wpqb,
        bq, bk, bv, bpk, bpq, qb, kb, vtb, pkb, pqb);

    // 3) MFMA flash attention (R15: PK/PQ staged, reg softmax), split-j x6
    attn_mfma<<<dim3(6, 12, 48), 256, 0, stream>>>(
        qb, kb, vtb, pkb, pqb, seg, sep, mask,
        same_bias, cross_bias, sep_scale, sep_decay, partO, partml);

    // 4) merge partials -> valsb
    merge_attn<<<dim3(576), 256, 0, stream>>>(partO, partml, valsb);

    // 5) output projection (64x128 tiles, 288 blocks)
    gemm_out<<<dim3(288), 256, 0, stream>>>(valsb, wob, bo, (float*)d_out);
}